// Round 4
// baseline (11671.326 us; speedup 1.0000x reference)
//
#include <hip/hip_runtime.h>
#include <stdint.h>

#define T_TOK 8192
#define DIM   2048
#define NEXP  16
#define NLAY  4
#define TOPK  8

#define BM 256
#define BN 256
#define BK 32
#define NT 64   // physical K-tiles; 3 terms fused per tile

typedef _Float16 f16;
typedef f16   f16x8 __attribute__((ext_vector_type(8)));
typedef f16   f16x4 __attribute__((ext_vector_type(4)));
typedef float f32x4 __attribute__((ext_vector_type(4)));
typedef float fv4   __attribute__((ext_vector_type(4)));

// ---------------- routing: fp32 logits, softmax, exact top-8 ----------------
__global__ __launch_bounds__(256) void route_kernel(
    const float* __restrict__ h, const float* __restrict__ gw,
    int* __restrict__ cnt, int* __restrict__ tok, float* __restrict__ wt)
{
  int gid  = blockIdx.x * 256 + threadIdx.x;
  int t    = gid >> 6;
  int lane = threadIdx.x & 63;
  if (t >= T_TOK) return;
  const float* hr = h + (size_t)t * DIM;
  float hreg[32];
#pragma unroll
  for (int j = 0; j < 32; ++j) hreg[j] = hr[lane + 64 * j];
  float p[16];
#pragma unroll
  for (int e = 0; e < 16; ++e) {
    const float* gr = gw + e * DIM;
    float s = 0.f;
#pragma unroll
    for (int j = 0; j < 32; ++j) s += hreg[j] * gr[lane + 64 * j];
#pragma unroll
    for (int off = 32; off; off >>= 1) s += __shfl_xor(s, off);
    p[e] = s;
  }
  float mx = p[0];
#pragma unroll
  for (int e = 1; e < 16; ++e) mx = fmaxf(mx, p[e]);
  float sum = 0.f;
#pragma unroll
  for (int e = 0; e < 16; ++e) { p[e] = expf(p[e] - mx); sum += p[e]; }
  float inv = 1.f / sum;
#pragma unroll
  for (int e = 0; e < 16; ++e) p[e] *= inv;
  if (lane < 16) {
    float mine = p[lane];
    int rank = 0;
#pragma unroll
    for (int j = 0; j < 16; ++j)
      rank += (p[j] > mine) || (p[j] == mine && j < lane);  // jax top_k tie-break
    if (rank < TOPK) {
      int pos = atomicAdd(&cnt[lane], 1);
      tok[lane * T_TOK + pos] = t;
      wt [lane * T_TOK + pos] = mine;
    }
  }
}

// ------------- fp32 -> scaled fp16 hi/lo split (x*64 = hi + lo) -------------
__global__ __launch_bounds__(256) void split_kernel(
    const float* __restrict__ src, f16* __restrict__ hi, f16* __restrict__ lo, int n4)
{
  int i0 = blockIdx.x * 256 + threadIdx.x;
  int stride = gridDim.x * 256;
  for (int i = i0; i < n4; i += stride) {
    fv4 v = ((const fv4*)src)[i];
    f16x4 h4, l4;
#pragma unroll
    for (int j = 0; j < 4; ++j) {
      float x = v[j] * 64.f;       // pre-scale keeps lo parts out of fp16 denormal range
      f16 hh = (f16)x;
      h4[j] = hh;
      l4[j] = (f16)(x - (float)hh);
    }
    ((f16x4*)hi)[i] = h4;
    ((f16x4*)lo)[i] = l4;
  }
}

// -------- gathered grouped GEMM, 256x256 tile, term-fused K-tiles -----------
// Per physical K-tile (BK=32): stage all 4 panels (A1,A2,W1,W2), read 24 frags,
// fire 96 MFMA (A1W1 + A1W2 + A2W1) -- frags reused from regs across terms.
// LDS layout is [chunk][row] (chunk-major, 4KB stride): every 16-lane frag
// group reads 256B contiguous => conflict-free, no swizzle; global_load_lds
// dest stays linear. 2 barriers per K-tile, counted vmcnt(8).
__global__ __launch_bounds__(512, 2) void moe_gemm(
    const f16* __restrict__ A1, const f16* __restrict__ A2,
    const f16* __restrict__ W1, const f16* __restrict__ W2,
    const int* __restrict__ tok, const float* __restrict__ wt,
    const int* __restrict__ cnt, float* __restrict__ out)
{
  const int e  = blockIdx.z;
  const int ce = cnt[e];
  const int m0 = blockIdx.y * BM;
  if (m0 >= ce) return;
  const int n0 = blockIdx.x * BN;

  __shared__ f16 lsA1[2][BM * BK];
  __shared__ f16 lsA2[2][BM * BK];
  __shared__ f16 lsB1[2][BN * BK];
  __shared__ f16 lsB2[2][BN * BK];

  const int tid = threadIdx.x;

  // staging: panel slot = g*512 + tid (g=0,1); layout [c][r]: c = g*2 + (tid>>8),
  // r = tid&255. LDS dest = slot*16B (linear). Global src = row r, k-chunk c.
  const int sr  = tid & 255;
  const int sc0 = tid >> 8;
  const int lpos = min(m0 + sr, ce - 1);
  const int gtok = tok[e * T_TOK + lpos];
  const size_t abase = (size_t)gtok * DIM;
  const size_t bbase = ((size_t)e * DIM + n0 + sr) * DIM;

  auto stage = [&](int kt, int b) {
    const int k0 = kt * BK;
#pragma unroll
    for (int g = 0; g < 2; ++g) {
      const int c   = g * 2 + sc0;
      const int dst = (g * 512 + tid) * 8;
      const size_t ao = abase + k0 + c * 8;
      const size_t bo = bbase + k0 + c * 8;
      __builtin_amdgcn_global_load_lds(
          (const __attribute__((address_space(1))) void*)(A1 + ao),
          (__attribute__((address_space(3))) void*)(&lsA1[b][dst]), 16, 0, 0);
      __builtin_amdgcn_global_load_lds(
          (const __attribute__((address_space(1))) void*)(A2 + ao),
          (__attribute__((address_space(3))) void*)(&lsA2[b][dst]), 16, 0, 0);
      __builtin_amdgcn_global_load_lds(
          (const __attribute__((address_space(1))) void*)(W1 + bo),
          (__attribute__((address_space(3))) void*)(&lsB1[b][dst]), 16, 0, 0);
      __builtin_amdgcn_global_load_lds(
          (const __attribute__((address_space(1))) void*)(W2 + bo),
          (__attribute__((address_space(3))) void*)(&lsB2[b][dst]), 16, 0, 0);
    }
  };

  const int lane = tid & 63;
  const int wid  = tid >> 6;
  const int wm   = wid & 1;           // M half (128 rows)
  const int wn   = wid >> 1;          // N quarter (64 cols)
  const int lr   = lane & 15;
  const int lk   = lane >> 4;         // 0..3 -> k-chunk

  f32x4 acc[8][4];
#pragma unroll
  for (int i = 0; i < 8; ++i)
#pragma unroll
    for (int j = 0; j < 4; ++j)
      acc[i][j] = (f32x4){0.f, 0.f, 0.f, 0.f};

  stage(0, 0);
  stage(1, 1);
  asm volatile("s_waitcnt vmcnt(8)" ::: "memory");
  __builtin_amdgcn_s_barrier();
  __builtin_amdgcn_sched_barrier(0);

  int cur = 0;
  for (int kt = 0; kt < NT; ++kt) {
    const f16* bA1 = lsA1[cur];
    const f16* bA2 = lsA2[cur];
    const f16* bB1 = lsB1[cur];
    const f16* bB2 = lsB2[cur];
    const bool pf = (kt + 2 < NT);
    f16x8 a1F[8], a2F[8], w1F[4], w2F[4];

    // ---- cluster 0: A1 x W1
#pragma unroll
    for (int mi = 0; mi < 8; ++mi) {
      int r = wm * 128 + mi * 16 + lr;
      a1F[mi] = *(const f16x8*)&bA1[lk * 2048 + r * 8];
    }
#pragma unroll
    for (int ni = 0; ni < 4; ++ni) {
      int r = wn * 64 + ni * 16 + lr;
      w1F[ni] = *(const f16x8*)&bB1[lk * 2048 + r * 8];
    }
    __builtin_amdgcn_s_setprio(1);
#pragma unroll
    for (int mi = 0; mi < 8; ++mi)
#pragma unroll
      for (int ni = 0; ni < 4; ++ni)
        acc[mi][ni] = __builtin_amdgcn_mfma_f32_16x16x32_f16(a1F[mi], w1F[ni], acc[mi][ni], 0, 0, 0);
    __builtin_amdgcn_s_setprio(0);

    // ---- cluster 1: A1 x W2 (A1 reused from regs)
#pragma unroll
    for (int ni = 0; ni < 4; ++ni) {
      int r = wn * 64 + ni * 16 + lr;
      w2F[ni] = *(const f16x8*)&bB2[lk * 2048 + r * 8];
    }
    __builtin_amdgcn_s_setprio(1);
#pragma unroll
    for (int mi = 0; mi < 8; ++mi)
#pragma unroll
      for (int ni = 0; ni < 4; ++ni)
        acc[mi][ni] = __builtin_amdgcn_mfma_f32_16x16x32_f16(a1F[mi], w2F[ni], acc[mi][ni], 0, 0, 0);
    __builtin_amdgcn_s_setprio(0);

    // ---- cluster 2: A2 x W1 (W1 reused); restage freed buffer first
#pragma unroll
    for (int mi = 0; mi < 8; ++mi) {
      int r = wm * 128 + mi * 16 + lr;
      a2F[mi] = *(const f16x8*)&bA2[lk * 2048 + r * 8];
    }
    asm volatile("s_waitcnt lgkmcnt(0)" ::: "memory");   // all my reads of buf[cur] done
    __builtin_amdgcn_sched_barrier(0);
    __builtin_amdgcn_s_barrier();                        // all waves done with buf[cur]
    __builtin_amdgcn_sched_barrier(0);
    if (pf) stage(kt + 2, cur);

    __builtin_amdgcn_s_setprio(1);
#pragma unroll
    for (int mi = 0; mi < 8; ++mi)
#pragma unroll
      for (int ni = 0; ni < 4; ++ni)
        acc[mi][ni] = __builtin_amdgcn_mfma_f32_16x16x32_f16(a2F[mi], w1F[ni], acc[mi][ni], 0, 0, 0);
    __builtin_amdgcn_s_setprio(0);

    if (kt + 1 < NT) {
      if (pf) asm volatile("s_waitcnt vmcnt(8)" ::: "memory");  // kt+1 landed, kt+2 in flight
      else    asm volatile("s_waitcnt vmcnt(0)" ::: "memory");
      __builtin_amdgcn_s_barrier();
      __builtin_amdgcn_sched_barrier(0);
    }
    cur ^= 1;
  }

  // epilogue: out[tok, n] += w * acc / 4096  (descale 64*64)
  const int ebase = e * T_TOK;
#pragma unroll
  for (int mi = 0; mi < 8; ++mi) {
#pragma unroll
    for (int q = 0; q < 4; ++q) {
      int pos = m0 + wm * 128 + mi * 16 + lk * 4 + q;
      if (pos < ce) {
        int tt = tok[ebase + pos];
        float sc = wt[ebase + pos] * (1.0f / 4096.0f);
        float* orow = out + (size_t)tt * DIM + n0 + wn * 64;
#pragma unroll
        for (int ni = 0; ni < 4; ++ni)
          atomicAdd(&orow[ni * 16 + lr], sc * acc[mi][ni][q]);
      }
    }
  }
}

// ------------------------------- launcher -----------------------------------
extern "C" void kernel_launch(void* const* d_in, const int* in_sizes, int n_in,
                              void* d_out, int out_size, void* d_ws, size_t ws_size,
                              hipStream_t stream) {
  const float* x  = (const float*)d_in[0];
  const float* gw = (const float*)d_in[1];
  const float* ew = (const float*)d_in[2];
  float* out = (float*)d_out;

  char* ws = (char*)d_ws;
  float* hA  = (float*)ws;                        // 64 MB fp32 h ping buffer
  f16*   A1  = (f16*)(ws + 67108864ull);          // 32 MB
  f16*   A2  = (f16*)(ws + 100663296ull);         // 32 MB
  f16*   W1  = (f16*)(ws + 134217728ull);         // 128 MB (current layer)
  f16*   W2  = (f16*)(ws + 268435456ull);         // 128 MB
  int*   tok = (int*)(ws + 402653184ull);         // 512 KB
  float* wt  = (float*)(ws + 403177472ull);       // 512 KB
  int*   cnt = (int*)(ws + 403701760ull);         // 64 B

  const float* hin = x;
  float* houts[4] = {hA, out, hA, out};           // ping-pong; final layer -> d_out
  for (int l = 0; l < NLAY; ++l) {
    float* hout = houts[l];
    hipMemsetAsync(cnt, 0, 64, stream);
    route_kernel<<<T_TOK / 4, 256, 0, stream>>>(hin, gw + (size_t)l * NEXP * DIM, cnt, tok, wt);
    split_kernel<<<4096, 256, 0, stream>>>(hin, A1, A2, T_TOK * DIM / 4);
    split_kernel<<<8192, 256, 0, stream>>>(ew + (size_t)l * NEXP * DIM * DIM, W1, W2, NEXP * DIM * DIM / 4);
    hipMemsetAsync(hout, 0, (size_t)T_TOK * DIM * 4, stream);
    dim3 g(DIM / BN, T_TOK / BM, NEXP);
    moe_gemm<<<g, 512, 0, stream>>>(A1, A2, W1, W2, tok, wt, cnt, hout);
    hin = hout;
  }
}

// Round 5
// 7997.891 us; speedup vs baseline: 1.4593x; 1.4593x over previous
//
#include <hip/hip_runtime.h>
#include <stdint.h>

#define T_TOK 8192
#define DIM   2048
#define NEXP  16
#define NLAY  4
#define TOPK  8

#define BM 256
#define BN 256
#define BK 32
#define NT 64   // physical K-tiles; 3 emulation terms fused inside each tile

typedef _Float16 f16;
typedef f16   f16x8 __attribute__((ext_vector_type(8)));
typedef f16   f16x4 __attribute__((ext_vector_type(4)));
typedef float f32x4 __attribute__((ext_vector_type(4)));
typedef float fv4   __attribute__((ext_vector_type(4)));

// ---------------- routing: fp32 logits, softmax, exact top-8 ----------------
__global__ __launch_bounds__(256) void route_kernel(
    const float* __restrict__ h, const float* __restrict__ gw,
    int* __restrict__ cnt, int* __restrict__ tok, float* __restrict__ wt)
{
  int gid  = blockIdx.x * 256 + threadIdx.x;
  int t    = gid >> 6;
  int lane = threadIdx.x & 63;
  if (t >= T_TOK) return;
  const float* hr = h + (size_t)t * DIM;
  float hreg[32];
#pragma unroll
  for (int j = 0; j < 32; ++j) hreg[j] = hr[lane + 64 * j];
  float p[16];
#pragma unroll
  for (int e = 0; e < 16; ++e) {
    const float* gr = gw + e * DIM;
    float s = 0.f;
#pragma unroll
    for (int j = 0; j < 32; ++j) s += hreg[j] * gr[lane + 64 * j];
#pragma unroll
    for (int off = 32; off; off >>= 1) s += __shfl_xor(s, off);
    p[e] = s;
  }
  float mx = p[0];
#pragma unroll
  for (int e = 1; e < 16; ++e) mx = fmaxf(mx, p[e]);
  float sum = 0.f;
#pragma unroll
  for (int e = 0; e < 16; ++e) { p[e] = expf(p[e] - mx); sum += p[e]; }
  float inv = 1.f / sum;
#pragma unroll
  for (int e = 0; e < 16; ++e) p[e] *= inv;
  if (lane < 16) {
    float mine = p[lane];
    int rank = 0;
#pragma unroll
    for (int j = 0; j < 16; ++j)
      rank += (p[j] > mine) || (p[j] == mine && j < lane);  // jax top_k tie-break
    if (rank < TOPK) {
      int pos = atomicAdd(&cnt[lane], 1);
      tok[lane * T_TOK + pos] = t;
      wt [lane * T_TOK + pos] = mine;
    }
  }
}

// ------- A: fp32 -> scaled fp16 hi/lo split (x*64 = hi + lo), row-major -----
__global__ __launch_bounds__(256) void split_kernel(
    const float* __restrict__ src, f16* __restrict__ hi, f16* __restrict__ lo, int n4)
{
  int i0 = blockIdx.x * 256 + threadIdx.x;
  int stride = gridDim.x * 256;
  for (int i = i0; i < n4; i += stride) {
    fv4 v = ((const fv4*)src)[i];
    f16x4 h4, l4;
#pragma unroll
    for (int j = 0; j < 4; ++j) {
      float x = v[j] * 64.f;       // pre-scale keeps lo parts out of fp16 denormal range
      f16 hh = (f16)x;
      h4[j] = hh;
      l4[j] = (f16)(x - (float)hh);
    }
    ((f16x4*)hi)[i] = h4;
    ((f16x4*)lo)[i] = l4;
  }
}

// ------- W: split + transpose to K-major-16B layout [E][K/8][2048][8] -------
// tile = 32 rows x 64 k of one expert; reads 256B-coalesced, writes 512B-coalesced.
__global__ __launch_bounds__(256) void wsplit_kernel(
    const float* __restrict__ src, f16* __restrict__ hi, f16* __restrict__ lo)
{
  const int eidx = blockIdx.z;
  const int r0   = blockIdx.y * 32;
  const int k0   = blockIdx.x * 64;
  __shared__ f16 th[32 * 9 * 8];   // [32 rows][9 chunk-slots (pad)][8 f16]
  __shared__ f16 tl[32 * 9 * 8];
  const int rr = threadIdx.x >> 3, c8 = threadIdx.x & 7;
  const float* s = src + ((size_t)eidx * DIM + r0 + rr) * DIM + k0 + c8 * 8;
  fv4 v0 = *(const fv4*)s;
  fv4 v1 = *(const fv4*)(s + 4);
  f16x8 hv, lv;
#pragma unroll
  for (int j = 0; j < 4; ++j) {
    float x = v0[j] * 64.f; f16 hh = (f16)x; hv[j] = hh; lv[j] = (f16)(x - (float)hh);
    float y = v1[j] * 64.f; f16 h2 = (f16)y; hv[4 + j] = h2; lv[4 + j] = (f16)(y - (float)h2);
  }
  *(f16x8*)&th[(rr * 9 + c8) * 8] = hv;
  *(f16x8*)&tl[(rr * 9 + c8) * 8] = lv;
  __syncthreads();
  const int c8w = threadIdx.x >> 5, rw = threadIdx.x & 31;
  f16x8 oh = *(const f16x8*)&th[(rw * 9 + c8w) * 8];
  f16x8 ol = *(const f16x8*)&tl[(rw * 9 + c8w) * 8];
  size_t o = (((size_t)eidx * (DIM / 8) + (k0 / 8 + c8w)) * DIM + r0 + rw) * 8;
  *(f16x8*)&hi[o] = oh;
  *(f16x8*)&lo[o] = ol;
}

// -------- gathered grouped GEMM, 256x256, BK=32, term-fused K-tiles ---------
// Per K-tile: stage A1,A2 (row-major, src-XOR-swizzled) + W1t,W2t (K-major,
// fully coalesced). Read 24 frags, fire 96 MFMA (A1W1 + A1W2 + A2W1) with
// register reuse across terms. 2 barriers/kt, counted vmcnt(8).
// 1D grid with XCD swizzle: the 8 N-blocks sharing an A-panel -> same XCD.
__global__ __launch_bounds__(512, 2) void moe_gemm(
    const f16* __restrict__ A1, const f16* __restrict__ A2,
    const f16* __restrict__ W1t, const f16* __restrict__ W2t,
    const int* __restrict__ tok, const float* __restrict__ wt,
    const int* __restrict__ cnt, float* __restrict__ out)
{
  // bid -> (expert, m-tile, n-tile) with XCD co-location of A-sharing blocks
  const int b  = blockIdx.x;
  const int g  = (b >> 6) * 8 + (b & 7);   // group id: (e, my)
  const int x  = (b >> 3) & 7;             // n-tile
  const int e  = g >> 5;
  const int ce = cnt[e];
  const int m0 = (g & 31) * BM;
  if (m0 >= ce) return;
  const int n0 = x * BN;

  __shared__ f16 lsA1[2][BM * BK];
  __shared__ f16 lsA2[2][BM * BK];
  __shared__ f16 lsW1[2][BN * BK];
  __shared__ f16 lsW2[2][BN * BK];

  const int tid = threadIdx.x;

  // A staging: slots {tid, tid+512}; slot s -> row s>>2, lane-chunk s&3.
  // Global source chunk = cl ^ ((row>>1)&3)  (involution; same for row+128).
  const int arow = tid >> 2;
  const int gc   = (tid & 3) ^ ((arow >> 1) & 3);
  const int lp0  = min(m0 + arow, ce - 1);
  const int lp1  = min(m0 + arow + 128, ce - 1);
  const size_t aofs0 = (size_t)tok[e * T_TOK + lp0] * DIM + gc * 8;
  const size_t aofs1 = (size_t)tok[e * T_TOK + lp1] * DIM + gc * 8;
  // W staging: slots {tid, tid+512}; slot s -> kchunk s>>8, row s&255.
  const int wc   = tid >> 8;           // 0..1 (slot2: +2)
  const int wrow = tid & 255;
  const size_t wbase = (size_t)e * (DIM / 8) * DIM * 8 + ((size_t)n0 + wrow) * 8;

  auto stage = [&](int kt, int bb) {
    const int k0  = kt * BK;
    const int kc0 = kt * 4;
    __builtin_amdgcn_global_load_lds(
        (const __attribute__((address_space(1))) void*)(A1 + aofs0 + k0),
        (__attribute__((address_space(3))) void*)(&lsA1[bb][tid * 8]), 16, 0, 0);
    __builtin_amdgcn_global_load_lds(
        (const __attribute__((address_space(1))) void*)(A1 + aofs1 + k0),
        (__attribute__((address_space(3))) void*)(&lsA1[bb][(tid + 512) * 8]), 16, 0, 0);
    __builtin_amdgcn_global_load_lds(
        (const __attribute__((address_space(1))) void*)(A2 + aofs0 + k0),
        (__attribute__((address_space(3))) void*)(&lsA2[bb][tid * 8]), 16, 0, 0);
    __builtin_amdgcn_global_load_lds(
        (const __attribute__((address_space(1))) void*)(A2 + aofs1 + k0),
        (__attribute__((address_space(3))) void*)(&lsA2[bb][(tid + 512) * 8]), 16, 0, 0);
    __builtin_amdgcn_global_load_lds(
        (const __attribute__((address_space(1))) void*)(W1t + wbase + (size_t)(kc0 + wc) * DIM * 8),
        (__attribute__((address_space(3))) void*)(&lsW1[bb][tid * 8]), 16, 0, 0);
    __builtin_amdgcn_global_load_lds(
        (const __attribute__((address_space(1))) void*)(W1t + wbase + (size_t)(kc0 + wc + 2) * DIM * 8),
        (__attribute__((address_space(3))) void*)(&lsW1[bb][(tid + 512) * 8]), 16, 0, 0);
    __builtin_amdgcn_global_load_lds(
        (const __attribute__((address_space(1))) void*)(W2t + wbase + (size_t)(kc0 + wc) * DIM * 8),
        (__attribute__((address_space(3))) void*)(&lsW2[bb][tid * 8]), 16, 0, 0);
    __builtin_amdgcn_global_load_lds(
        (const __attribute__((address_space(1))) void*)(W2t + wbase + (size_t)(kc0 + wc + 2) * DIM * 8),
        (__attribute__((address_space(3))) void*)(&lsW2[bb][(tid + 512) * 8]), 16, 0, 0);
  };

  const int lane = tid & 63;
  const int wid  = tid >> 6;
  const int wm   = wid & 1;           // M half (128 rows)
  const int wn   = wid >> 1;          // N quarter (64 cols)
  const int lr   = lane & 15;
  const int lk   = lane >> 4;         // 0..3 -> k-chunk
  const int aswz = lk ^ ((lr >> 1) & 3);  // A-read chunk swizzle (per-thread const)

  f32x4 acc[8][4];
#pragma unroll
  for (int i = 0; i < 8; ++i)
#pragma unroll
    for (int j = 0; j < 4; ++j)
      acc[i][j] = (f32x4){0.f, 0.f, 0.f, 0.f};

  stage(0, 0);
  stage(1, 1);
  asm volatile("s_waitcnt vmcnt(8)" ::: "memory");
  __builtin_amdgcn_s_barrier();
  __builtin_amdgcn_sched_barrier(0);

  int cur = 0;
  for (int kt = 0; kt < NT; ++kt) {
    const f16* bA1 = lsA1[cur];
    const f16* bA2 = lsA2[cur];
    const f16* bW1 = lsW1[cur];
    const f16* bW2 = lsW2[cur];
    const bool pf = (kt + 2 < NT);
    f16x8 aF[8], w1F[4], w2F[4];

    // ---- cluster 0: A1 x W1
#pragma unroll
    for (int mi = 0; mi < 8; ++mi) {
      int r = wm * 128 + mi * 16 + lr;
      aF[mi] = *(const f16x8*)&bA1[r * 32 + aswz * 8];
    }
#pragma unroll
    for (int ni = 0; ni < 4; ++ni) {
      int r = wn * 64 + ni * 16 + lr;
      w1F[ni] = *(const f16x8*)&bW1[lk * 2048 + r * 8];
    }
    __builtin_amdgcn_s_setprio(1);
#pragma unroll
    for (int mi = 0; mi < 8; ++mi)
#pragma unroll
      for (int ni = 0; ni < 4; ++ni)
        acc[mi][ni] = __builtin_amdgcn_mfma_f32_16x16x32_f16(aF[mi], w1F[ni], acc[mi][ni], 0, 0, 0);
    __builtin_amdgcn_s_setprio(0);

    // ---- cluster 1: A1 x W2 (A1 reused from regs)
#pragma unroll
    for (int ni = 0; ni < 4; ++ni) {
      int r = wn * 64 + ni * 16 + lr;
      w2F[ni] = *(const f16x8*)&bW2[lk * 2048 + r * 8];
    }
    __builtin_amdgcn_s_setprio(1);
#pragma unroll
    for (int mi = 0; mi < 8; ++mi)
#pragma unroll
      for (int ni = 0; ni < 4; ++ni)
        acc[mi][ni] = __builtin_amdgcn_mfma_f32_16x16x32_f16(aF[mi], w2F[ni], acc[mi][ni], 0, 0, 0);
    __builtin_amdgcn_s_setprio(0);

    // ---- cluster 2: A2 x W1 (W1 reused); aF regs reloaded with A2
#pragma unroll
    for (int mi = 0; mi < 8; ++mi) {
      int r = wm * 128 + mi * 16 + lr;
      aF[mi] = *(const f16x8*)&bA2[r * 32 + aswz * 8];
    }
    asm volatile("s_waitcnt lgkmcnt(0)" ::: "memory");   // all my reads of buf[cur] done
    __builtin_amdgcn_sched_barrier(0);
    __builtin_amdgcn_s_barrier();                        // all waves done with buf[cur]
    __builtin_amdgcn_sched_barrier(0);
    if (pf) stage(kt + 2, cur);

    __builtin_amdgcn_s_setprio(1);
#pragma unroll
    for (int mi = 0; mi < 8; ++mi)
#pragma unroll
      for (int ni = 0; ni < 4; ++ni)
        acc[mi][ni] = __builtin_amdgcn_mfma_f32_16x16x32_f16(aF[mi], w1F[ni], acc[mi][ni], 0, 0, 0);
    __builtin_amdgcn_s_setprio(0);

    if (kt + 1 < NT) {
      if (pf) asm volatile("s_waitcnt vmcnt(8)" ::: "memory");  // kt+1 landed, kt+2 in flight
      else    asm volatile("s_waitcnt vmcnt(0)" ::: "memory");
      __builtin_amdgcn_s_barrier();
      __builtin_amdgcn_sched_barrier(0);
    }
    cur ^= 1;
  }

  // epilogue: out[tok, n] += w * acc / 4096  (descale 64*64)
  const int ebase = e * T_TOK;
#pragma unroll
  for (int mi = 0; mi < 8; ++mi) {
#pragma unroll
    for (int q = 0; q < 4; ++q) {
      int pos = m0 + wm * 128 + mi * 16 + lk * 4 + q;
      if (pos < ce) {
        int tt = tok[ebase + pos];
        float sc = wt[ebase + pos] * (1.0f / 4096.0f);
        float* orow = out + (size_t)tt * DIM + n0 + wn * 64;
#pragma unroll
        for (int ni = 0; ni < 4; ++ni)
          atomicAdd(&orow[ni * 16 + lr], sc * acc[mi][ni][q]);
      }
    }
  }
}

// ------------------------------- launcher -----------------------------------
extern "C" void kernel_launch(void* const* d_in, const int* in_sizes, int n_in,
                              void* d_out, int out_size, void* d_ws, size_t ws_size,
                              hipStream_t stream) {
  const float* x  = (const float*)d_in[0];
  const float* gw = (const float*)d_in[1];
  const float* ew = (const float*)d_in[2];
  float* out = (float*)d_out;

  char* ws = (char*)d_ws;
  float* hA  = (float*)ws;                        // 64 MB fp32 h ping buffer
  f16*   A1  = (f16*)(ws + 67108864ull);          // 32 MB
  f16*   A2  = (f16*)(ws + 100663296ull);         // 32 MB
  f16*   W1t = (f16*)(ws + 134217728ull);         // 128 MB (K-major, this layer)
  f16*   W2t = (f16*)(ws + 268435456ull);         // 128 MB
  int*   tok = (int*)(ws + 402653184ull);         // 512 KB
  float* wt  = (float*)(ws + 403177472ull);       // 512 KB
  int*   cnt = (int*)(ws + 403701760ull);         // 64 B

  const float* hin = x;
  float* houts[4] = {hA, out, hA, out};           // ping-pong; final layer -> d_out
  for (int l = 0; l < NLAY; ++l) {
    float* hout = houts[l];
    hipMemsetAsync(cnt, 0, 64, stream);
    route_kernel<<<T_TOK / 4, 256, 0, stream>>>(hin, gw + (size_t)l * NEXP * DIM, cnt, tok, wt);
    split_kernel<<<4096, 256, 0, stream>>>(hin, A1, A2, T_TOK * DIM / 4);
    {
      dim3 gt(DIM / 64, DIM / 32, NEXP);
      wsplit_kernel<<<gt, 256, 0, stream>>>(ew + (size_t)l * NEXP * DIM * DIM, W1t, W2t);
    }
    hipMemsetAsync(hout, 0, (size_t)T_TOK * DIM * 4, stream);
    moe_gemm<<<(DIM / BN) * (T_TOK / BM) * NEXP, 512, 0, stream>>>(
        A1, A2, W1t, W2t, tok, wt, cnt, hout);
    hin = hout;
  }
}